// Round 8
// baseline (685.387 us; speedup 1.0000x reference)
//
#include <hip/hip_runtime.h>
#include <hip/hip_fp16.h>
#include <hip/hip_cooperative_groups.h>
#include <math.h>

namespace cg = cooperative_groups;

// Problem constants
constexpr int N    = 50000;
constexpr int E    = 1600000;
constexpr int F    = 256;        // HEADS*HID
constexpr int EL   = E + N;      // edges + self loops
constexpr int NBLK = (N + 255) / 256;  // 196 scan blocks
constexpr int CH   = (EL + 15) / 16;   // 16-edge score chunks

typedef _Float16 v8hf __attribute__((ext_vector_type(8)));
typedef float    v4f  __attribute__((ext_vector_type(4)));

// ---------------------------------------------------------------------------
// ONE cooperative kernel for all CSR/prep work (196 blocks x 256, co-resident):
//   phase P: wt = W^T fp16, wt3h = (0.5*fc1W)^T fp16 (16-col padded), zero counts
//   phase H: dst-degree histogram (grid-stride atomics)
//   phase S1: per-block exclusive scan of counts(+1 self loop)
//   phase S2: each block redundantly scans the 196 partials, adds prefix
//   phase S3: scatter se[pos] = (src, eid, dst, 0), eid=-1 for self loops
// Replaces 5 dispatches (prep/hist/scan1/scan3b/scatter) with 1.
// ---------------------------------------------------------------------------
__global__ __launch_bounds__(256) void k_csr(
    const int* __restrict__ ei, const float* __restrict__ W,
    const float* __restrict__ fc1W, _Float16* __restrict__ wt,
    _Float16* __restrict__ wt3h, int* __restrict__ counts,
    int* __restrict__ offsets, int* __restrict__ partials,
    int* __restrict__ cursor, int4* __restrict__ se) {
  cg::grid_group grid = cg::this_grid();
  const int t = threadIdx.x, b = blockIdx.x;
  const int gid = b * 256 + t;                 // 50176 threads
  constexpr int GT = NBLK * 256;

  // P: weight transposes + zero counts
  for (int i = gid; i < F * F; i += GT) {
    const int n = i >> 8, k = i & 255;
    wt[i] = (_Float16)W[k * 256 + n];
  }
  if (gid < 4096) {
    const int n = gid >> 8, k = gid & 255;
    wt3h[gid] = (n < 3) ? (_Float16)(0.5f * fc1W[k * 3 + n]) : (_Float16)0.f;
  }
  if (gid < N) counts[gid] = 0;
  grid.sync();

  // H: histogram of dst
  for (int i = gid; i < E; i += GT) atomicAdd(&counts[ei[E + i]], 1);
  grid.sync();

  // S1: block-local exclusive scan
  __shared__ int s[256];
  const int v = (gid < N) ? counts[gid] + 1 : 0;   // +1 = self loop
  s[t] = v;
  __syncthreads();
  for (int off = 1; off < 256; off <<= 1) {
    const int add = (t >= off) ? s[t - off] : 0;
    __syncthreads();
    s[t] += add;
    __syncthreads();
  }
  if (gid < N) offsets[gid] = s[t] - v;
  if (t == 255) partials[b] = s[255];
  grid.sync();

  // S2: scan partials (each block redundantly), add prefix, init cursor
  {
    const int pv = (t < NBLK) ? partials[t] : 0;
    __syncthreads();
    s[t] = pv;
    __syncthreads();
    for (int off = 1; off < 256; off <<= 1) {
      const int add = (t >= off) ? s[t - off] : 0;
      __syncthreads();
      s[t] += add;
      __syncthreads();
    }
    const int pre = (b == 0) ? 0 : s[b - 1];
    if (gid < N) {
      const int val = offsets[gid] + pre;
      offsets[gid] = val;
      cursor[gid]  = val;
    }
    if (gid == 0) offsets[N] = EL;
  }
  grid.sync();

  // S3: scatter
  for (int i = gid; i < EL; i += GT) {
    int sn, d, id;
    if (i < E) { sn = ei[i]; d = ei[E + i]; id = i; }
    else       { sn = d = i - E; id = -1; }
    const int pos = atomicAdd(&cursor[d], 1);
    se[pos] = make_int4(sn, id, d, 0);
  }
}

// ---------------------------------------------------------------------------
// xp = x @ W via MFMA 16x16x32 f16 (fp32 accumulate), fp32 x converted inline.
// Block = 256 thr = 4 waves; wave w owns cols 64w..64w+63 (== head w) of a
// 16-row strip. Epilogue: xp fp16; a_src/a_dst from fp32 accumulators.
// ---------------------------------------------------------------------------
__global__ __launch_bounds__(256) void k_xw_mfma(
    const float* __restrict__ x, const _Float16* __restrict__ wt,
    const float* __restrict__ att_src, const float* __restrict__ att_dst,
    __half* __restrict__ xp, float* __restrict__ a_src, float* __restrict__ a_dst) {
  const int wv   = threadIdx.x >> 6;
  const int lane = threadIdx.x & 63;
  const int q = lane >> 4, l16 = lane & 15;
  const int m0 = blockIdx.x * 16;
  const int c0 = wv * 64;

  v4f acc[4] = {{0,0,0,0},{0,0,0,0},{0,0,0,0},{0,0,0,0}};
  const float*    arow = x  + (size_t)(m0 + l16) * 256 + q * 8;
  const _Float16* brow = wt + (size_t)(c0 + l16) * 256 + q * 8;

  for (int kc = 0; kc < 256; kc += 32) {
    const float4 f0 = *(const float4*)(arow + kc);
    const float4 f1 = *(const float4*)(arow + kc + 4);
    const v8hf a = {(_Float16)f0.x, (_Float16)f0.y, (_Float16)f0.z, (_Float16)f0.w,
                    (_Float16)f1.x, (_Float16)f1.y, (_Float16)f1.z, (_Float16)f1.w};
    #pragma unroll
    for (int tn = 0; tn < 4; ++tn) {
      const v8hf bfr = *(const v8hf*)(brow + (size_t)tn * 16 * 256 + kc);
      acc[tn] = __builtin_amdgcn_mfma_f32_16x16x32_f16(a, bfr, acc[tn], 0, 0, 0);
    }
  }

  #pragma unroll
  for (int tn = 0; tn < 4; ++tn) {
    const int col = c0 + tn * 16 + l16;
    #pragma unroll
    for (int r = 0; r < 4; ++r)
      xp[(size_t)(m0 + q * 4 + r) * 256 + col] = __float2half_rn(acc[tn][r]);
  }

  float aw[4], dw[4];
  #pragma unroll
  for (int tn = 0; tn < 4; ++tn) {
    aw[tn] = att_src[c0 + tn * 16 + l16];
    dw[tn] = att_dst[c0 + tn * 16 + l16];
  }
  #pragma unroll
  for (int r = 0; r < 4; ++r) {
    float ps = acc[0][r]*aw[0] + acc[1][r]*aw[1] + acc[2][r]*aw[2] + acc[3][r]*aw[3];
    float pd = acc[0][r]*dw[0] + acc[1][r]*dw[1] + acc[2][r]*dw[2] + acc[3][r]*dw[3];
    #pragma unroll
    for (int off = 1; off < 16; off <<= 1) {
      ps += __shfl_xor(ps, off, 16);
      pd += __shfl_xor(pd, off, 16);
    }
    if (l16 == 0) {
      a_src[(m0 + q * 4 + r) * 4 + wv] = ps;
      a_dst[(m0 + q * 4 + r) * 4 + wv] = pd;
    }
  }
}

// ---------------------------------------------------------------------------
// Segment softmax + aggregation + bias + leaky. One block (2 waves) per node;
// waves split the 16-edge chunks, LDS-combine at end. Lane owns features
// 4L..4L+3; weights computed by 16 lane-slots per head, __shfl broadcast.
// Gathers 8-deep in flight.
// ---------------------------------------------------------------------------
__global__ __launch_bounds__(128) void k_agg(
    const __half* __restrict__ xp, const float* __restrict__ a_src,
    const float* __restrict__ a_dst, const int4* __restrict__ se,
    const int* __restrict__ offsets, const float* __restrict__ bias,
    __half* __restrict__ h) {
  const int n = blockIdx.x;
  const int t = threadIdx.x;              // 0..127
  const int wv = t >> 6, lane = t & 63;
  const int hd = lane >> 4, es = lane & 15;
  const int beg = offsets[n], end = offsets[n + 1];
  const float adst = a_dst[n * 4 + hd];
  const __half* xb = xp + (size_t)lane * 4;

  float a0 = 0.f, a1 = 0.f, a2 = 0.f, a3 = 0.f, den = 0.f;

  for (int c = beg + wv * 16; c < end; c += 32) {
    const int cnt = min(16, end - c);
    int sv = 0; float wvv = 0.f;
    if (es < cnt) {
      sv = se[c + es].x;
      float al = a_src[sv * 4 + hd] + adst;
      al = al > 0.f ? al : 0.2f * al;
      wvv = __expf(al);
    }
    if (cnt == 16) {
      #pragma unroll
      for (int g = 0; g < 2; ++g) {
        int ss[8]; float ww[8]; uint2 rr[8];
        #pragma unroll
        for (int j = 0; j < 8; ++j) {
          ss[j] = __shfl(sv,  g * 8 + j, 16);
          ww[j] = __shfl(wvv, g * 8 + j, 16);
        }
        #pragma unroll
        for (int j = 0; j < 8; ++j) rr[j] = *(const uint2*)(xb + (size_t)ss[j] * 256);
        #pragma unroll
        for (int j = 0; j < 8; ++j) {
          const __half2* p = (const __half2*)&rr[j];
          const float2 lo = __half22float2(p[0]), hi = __half22float2(p[1]);
          den += ww[j];
          a0 += ww[j] * lo.x; a1 += ww[j] * lo.y;
          a2 += ww[j] * hi.x; a3 += ww[j] * hi.y;
        }
      }
    } else {
      for (int j = 0; j < cnt; ++j) {
        const int   s = __shfl(sv, j, 16);
        const float w = __shfl(wvv, j, 16);
        const uint2 r = *(const uint2*)(xb + (size_t)s * 256);
        const __half2* p = (const __half2*)&r;
        const float2 lo = __half22float2(p[0]), hi = __half22float2(p[1]);
        den += w;
        a0 += w * lo.x; a1 += w * lo.y; a2 += w * hi.x; a3 += w * hi.y;
      }
    }
  }

  __shared__ float ra[256];
  __shared__ float rd[64];
  if (wv == 1) {
    ra[lane * 4 + 0] = a0; ra[lane * 4 + 1] = a1;
    ra[lane * 4 + 2] = a2; ra[lane * 4 + 3] = a3;
    rd[lane] = den;
  }
  __syncthreads();
  if (wv == 0) {
    a0 += ra[lane * 4 + 0]; a1 += ra[lane * 4 + 1];
    a2 += ra[lane * 4 + 2]; a3 += ra[lane * 4 + 3];
    den += rd[lane];
    const float inv = 1.f / (den + 1e-16f);
    const float4 bv = *(const float4*)(bias + lane * 4);
    float o0 = a0 * inv + bv.x, o1 = a1 * inv + bv.y;
    float o2 = a2 * inv + bv.z, o3 = a3 * inv + bv.w;
    o0 = o0 > 0.f ? o0 : 0.01f * o0;
    o1 = o1 > 0.f ? o1 : 0.01f * o1;
    o2 = o2 > 0.f ? o2 : 0.01f * o2;
    o3 = o3 > 0.f ? o3 : 0.01f * o3;
    const __half2 p0 = __floats2half2_rn(o0, o1), p1 = __floats2half2_rn(o2, o3);
    uint2 st;
    st.x = *(const unsigned*)&p0;
    st.y = *(const unsigned*)&p1;
    *(uint2*)(h + (size_t)n * 256 + lane * 4) = st;
  }
}

// ---------------------------------------------------------------------------
// Edge scoring via MFMA over FLAT 16-edge chunks of the CSR array. dst-row
// loads cache-hot (consecutive edges share dst). 17 independent loads per
// lane per chunk. C: row=edge slot (q*4+r), col=score idx.
// ---------------------------------------------------------------------------
__global__ __launch_bounds__(256) void k_score_flat(
    const _Float16* __restrict__ h, const int4* __restrict__ se,
    const _Float16* __restrict__ wt3h, const float* __restrict__ fc1b,
    float* __restrict__ out, int total_waves) {
  const int lane = threadIdx.x & 63;
  const int q = lane >> 4, l16 = lane & 15;
  const int wgid = blockIdx.x * 4 + (threadIdx.x >> 6);

  v8hf bfrag[8];
  {
    const _Float16* brow = wt3h + l16 * 256 + q * 8;
    #pragma unroll
    for (int kci = 0; kci < 8; ++kci) bfrag[kci] = *(const v8hf*)(brow + kci * 32);
  }
  const float bn = (l16 < 3) ? fc1b[l16] : 0.f;

  for (int ch = wgid; ch < CH; ch += total_waves) {
    const int idx = ch * 16 + l16;
    int s = 0, d = 0, eid = -1;
    if (idx < EL) { const int4 p = se[idx]; s = p.x; eid = p.y; d = p.z; }

    const _Float16* srow = h + (size_t)s * 256 + q * 8;
    const _Float16* drow = h + (size_t)d * 256 + q * 8;
    v8hf av[8], dv[8];
    #pragma unroll
    for (int kci = 0; kci < 8; ++kci) av[kci] = *(const v8hf*)(srow + kci * 32);
    #pragma unroll
    for (int kci = 0; kci < 8; ++kci) dv[kci] = *(const v8hf*)(drow + kci * 32);

    v4f acc = {0.f, 0.f, 0.f, 0.f};
    #pragma unroll
    for (int kci = 0; kci < 8; ++kci) {
      const v8hf ar = av[kci] * dv[kci];     // v_pk_mul_f16 x4
      acc = __builtin_amdgcn_mfma_f32_16x16x32_f16(ar, bfrag[kci], acc, 0, 0, 0);
    }

    #pragma unroll
    for (int r = 0; r < 4; ++r) {
      const int m = q * 4 + r;
      const int em = __shfl(eid, m, 16);     // eid lives in lane l16==m of group
      if (l16 < 3 && em >= 0)
        out[(size_t)em * 3 + l16] = acc[r] + bn;
    }
  }
}

// ---------------------------------------------------------------------------
static inline size_t align256(size_t b) { return (b + 255) & ~(size_t)255; }

extern "C" void kernel_launch(void* const* d_in, const int* in_sizes, int n_in,
                              void* d_out, int out_size, void* d_ws, size_t ws_size,
                              hipStream_t stream) {
  const float* x    = (const float*)d_in[0];
  const int*   ei   = (const int*)  d_in[1];   // [2,E] flat: [0:E]=src, [E:2E]=dst
  const float* W    = (const float*)d_in[2];
  const float* attS = (const float*)d_in[3];
  const float* attD = (const float*)d_in[4];
  const float* bias = (const float*)d_in[5];
  const float* fc1W = (const float*)d_in[6];
  const float* fc1b = (const float*)d_in[7];
  float*       out  = (float*)d_out;
  char*        ws   = (char*)d_ws;

  size_t off = 0;
  auto alloc = [&](size_t bytes) -> void* {
    void* p = ws + off;
    off += align256(bytes);
    return p;
  };
  _Float16* wt     = (_Float16*)alloc((size_t)F * F * sizeof(_Float16));  // 128 KB
  _Float16* wt3h   = (_Float16*)alloc((size_t)16 * F * sizeof(_Float16)); // 8 KB
  __half*   xp     = (__half*)  alloc((size_t)N * F * sizeof(__half));    // 25.6 MB
  __half*   hbuf   = (__half*)  alloc((size_t)N * F * sizeof(__half));    // 25.6 MB
  float*    a_src  = (float*)   alloc((size_t)N * 4 * sizeof(float));
  float*    a_dst  = (float*)   alloc((size_t)N * 4 * sizeof(float));
  int*      counts = (int*)     alloc((size_t)N * sizeof(int));
  int*      offs   = (int*)     alloc((size_t)(N + 1) * sizeof(int));
  int*      partial= (int*)     alloc(256 * sizeof(int));
  int*      cursor = (int*)     alloc((size_t)N * sizeof(int));
  int4*     se     = (int4*)    alloc((size_t)EL * sizeof(int4));         // 26.4 MB

  // 1) cooperative CSR/prep kernel (196 co-resident blocks, grid.sync phases)
  {
    void* args[] = {(void*)&ei, (void*)&W, (void*)&fc1W, (void*)&wt, (void*)&wt3h,
                    (void*)&counts, (void*)&offs, (void*)&partial, (void*)&cursor,
                    (void*)&se};
    hipLaunchCooperativeKernel((const void*)k_csr, dim3(NBLK), dim3(256),
                               args, 0, stream);
  }
  // 2) GEMM (independent of CSR except stream order; wt produced by k_csr)
  k_xw_mfma<<<N / 16, 256, 0, stream>>>(x, wt, attS, attD, xp, a_src, a_dst);
  // 3) aggregation
  k_agg<<<N, 128, 0, stream>>>(xp, a_src, a_dst, se, offs, bias, hbuf);
  // 4) edge scoring
  const int score_blocks = 4096;
  k_score_flat<<<score_blocks, 256, 0, stream>>>((const _Float16*)hbuf, se, wt3h,
                                                 fc1b, out, score_blocks * 4);
}

// Round 9
// 610.894 us; speedup vs baseline: 1.1219x; 1.1219x over previous
//
#include <hip/hip_runtime.h>
#include <hip/hip_fp16.h>
#include <math.h>

// Problem constants
constexpr int N    = 50000;
constexpr int E    = 1600000;
constexpr int F    = 256;        // HEADS*HID
constexpr int EL   = E + N;      // edges + self loops
constexpr int NBLK = (N + 255) / 256;  // 196 scan blocks
constexpr int CH   = (EL + 15) / 16;   // 16-edge score chunks

typedef _Float16 v8hf __attribute__((ext_vector_type(8)));
typedef float    v4f  __attribute__((ext_vector_type(4)));

// ---------------------------------------------------------------------------
// Prep: wt = W^T fp16; wt3h = (0.5*fc1W)^T fp16 padded to 16 cols; zero counts.
// ---------------------------------------------------------------------------
__global__ __launch_bounds__(256) void k_prep(
    const float* __restrict__ W, const float* __restrict__ fc1W,
    _Float16* __restrict__ wt, _Float16* __restrict__ wt3h,
    int* __restrict__ counts) {
  const int t = blockIdx.x * 256 + threadIdx.x;    // 65536 threads
  {
    const int n = t >> 8, k = t & 255;
    wt[t] = (_Float16)W[k * 256 + n];
  }
  if (t < 4096) {
    const int n = t >> 8, k = t & 255;
    wt3h[t] = (n < 3) ? (_Float16)(0.5f * fc1W[k * 3 + n]) : (_Float16)0.f;
  }
  if (t < N) counts[t] = 0;
}

// ---------------------------------------------------------------------------
// xp = x @ W via MFMA 16x16x32 f16 (fp32 accumulate), fp32 x converted inline.
// Tail: grid-stride dst histogram (counts zeroed by k_prep, prior launch).
// ---------------------------------------------------------------------------
__global__ __launch_bounds__(256) void k_xw_mfma(
    const float* __restrict__ x, const _Float16* __restrict__ wt,
    const float* __restrict__ att_src, const float* __restrict__ att_dst,
    const int* __restrict__ ei, int* __restrict__ counts,
    __half* __restrict__ xp, float* __restrict__ a_src, float* __restrict__ a_dst) {
  const int wv   = threadIdx.x >> 6;
  const int lane = threadIdx.x & 63;
  const int q = lane >> 4, l16 = lane & 15;
  const int m0 = blockIdx.x * 16;
  const int c0 = wv * 64;

  v4f acc[4] = {{0,0,0,0},{0,0,0,0},{0,0,0,0},{0,0,0,0}};
  const float*    arow = x  + (size_t)(m0 + l16) * 256 + q * 8;
  const _Float16* brow = wt + (size_t)(c0 + l16) * 256 + q * 8;

  for (int kc = 0; kc < 256; kc += 32) {
    const float4 f0 = *(const float4*)(arow + kc);
    const float4 f1 = *(const float4*)(arow + kc + 4);
    const v8hf a = {(_Float16)f0.x, (_Float16)f0.y, (_Float16)f0.z, (_Float16)f0.w,
                    (_Float16)f1.x, (_Float16)f1.y, (_Float16)f1.z, (_Float16)f1.w};
    #pragma unroll
    for (int tn = 0; tn < 4; ++tn) {
      const v8hf b = *(const v8hf*)(brow + (size_t)tn * 16 * 256 + kc);
      acc[tn] = __builtin_amdgcn_mfma_f32_16x16x32_f16(a, b, acc[tn], 0, 0, 0);
    }
  }

  #pragma unroll
  for (int tn = 0; tn < 4; ++tn) {
    const int col = c0 + tn * 16 + l16;
    #pragma unroll
    for (int r = 0; r < 4; ++r)
      xp[(size_t)(m0 + q * 4 + r) * 256 + col] = __float2half_rn(acc[tn][r]);
  }

  float aw[4], dw[4];
  #pragma unroll
  for (int tn = 0; tn < 4; ++tn) {
    aw[tn] = att_src[c0 + tn * 16 + l16];
    dw[tn] = att_dst[c0 + tn * 16 + l16];
  }
  #pragma unroll
  for (int r = 0; r < 4; ++r) {
    float ps = acc[0][r]*aw[0] + acc[1][r]*aw[1] + acc[2][r]*aw[2] + acc[3][r]*aw[3];
    float pd = acc[0][r]*dw[0] + acc[1][r]*dw[1] + acc[2][r]*dw[2] + acc[3][r]*dw[3];
    #pragma unroll
    for (int off = 1; off < 16; off <<= 1) {
      ps += __shfl_xor(ps, off, 16);
      pd += __shfl_xor(pd, off, 16);
    }
    if (l16 == 0) {
      a_src[(m0 + q * 4 + r) * 4 + wv] = ps;
      a_dst[(m0 + q * 4 + r) * 4 + wv] = pd;
    }
  }

  // dst-degree histogram tail (grid = 3125*256 = 800000 threads)
  const int gid = blockIdx.x * 256 + threadIdx.x;
  for (int i = gid; i < E; i += 800000) atomicAdd(&counts[ei[E + i]], 1);
}

// ---------------------------------------------------------------------------
// CSR: scan1 -> scan3b -> scatter (wide grids; latency-bound phases need
// full-device parallelism — coop/grid.sync version regressed, R8 post-mortem).
// ---------------------------------------------------------------------------
__global__ __launch_bounds__(256) void k_scan1(
    const int* __restrict__ counts, int* __restrict__ offsets, int* __restrict__ partials) {
  __shared__ int s[256];
  const int t = threadIdx.x;
  const int i = blockIdx.x * 256 + t;
  const int v = (i < N) ? counts[i] + 1 : 0;     // +1 = self loop
  s[t] = v;
  __syncthreads();
  for (int off = 1; off < 256; off <<= 1) {
    const int add = (t >= off) ? s[t - off] : 0;
    __syncthreads();
    s[t] += add;
    __syncthreads();
  }
  if (i < N) offsets[i] = s[t] - v;              // local exclusive
  if (t == 255) partials[blockIdx.x] = s[255];   // block total
}

__global__ __launch_bounds__(256) void k_scan3b(
    int* __restrict__ offsets, const int* __restrict__ partials,
    int* __restrict__ cursor) {
  __shared__ int s[256];
  const int t = threadIdx.x, b = blockIdx.x;
  const int v = (t < NBLK) ? partials[t] : 0;
  s[t] = v;
  __syncthreads();
  for (int off = 1; off < 256; off <<= 1) {
    const int add = (t >= off) ? s[t - off] : 0;
    __syncthreads();
    s[t] += add;
    __syncthreads();
  }
  const int pre = (b == 0) ? 0 : s[b - 1];       // sum of partials[0..b-1]
  const int i = b * 256 + t;
  if (i < N) {
    const int val = offsets[i] + pre;
    offsets[i] = val;
    cursor[i]  = val;
  }
  if (i == 0) offsets[N] = EL;
}

// se[pos] = (src, eid, dst, 0); eid=-1 for self loops (no score output)
__global__ void k_scatter(const int* __restrict__ ei, int* __restrict__ cursor,
                          int4* __restrict__ se) {
  const int i = blockIdx.x * blockDim.x + threadIdx.x;
  if (i >= EL) return;
  int s, d, id;
  if (i < E) { s = ei[i]; d = ei[E + i]; id = i; }
  else       { s = d = i - E; id = -1; }
  const int pos = atomicAdd(&cursor[d], 1);
  se[pos] = make_int4(s, id, d, 0);
}

// ---------------------------------------------------------------------------
// Segment softmax + aggregation + bias + leaky. One block (2 waves) per node;
// waves split the 16-edge chunks, LDS-combine at end. Gathers 16-deep in
// flight (full chunk issued before any consumption).
// ---------------------------------------------------------------------------
__global__ __launch_bounds__(128) void k_agg(
    const __half* __restrict__ xp, const float* __restrict__ a_src,
    const float* __restrict__ a_dst, const int4* __restrict__ se,
    const int* __restrict__ offsets, const float* __restrict__ bias,
    __half* __restrict__ h) {
  const int n = blockIdx.x;
  const int t = threadIdx.x;              // 0..127
  const int wv = t >> 6, lane = t & 63;
  const int hd = lane >> 4, es = lane & 15;
  const int beg = offsets[n], end = offsets[n + 1];
  const float adst = a_dst[n * 4 + hd];
  const __half* xb = xp + (size_t)lane * 4;

  float a0 = 0.f, a1 = 0.f, a2 = 0.f, a3 = 0.f, den = 0.f;

  for (int c = beg + wv * 16; c < end; c += 32) {
    const int cnt = min(16, end - c);
    int sv = 0; float wvv = 0.f;
    if (es < cnt) {
      sv = se[c + es].x;
      float al = a_src[sv * 4 + hd] + adst;
      al = al > 0.f ? al : 0.2f * al;
      wvv = __expf(al);
    }
    if (cnt == 16) {
      int ss[16]; float ww[16]; uint2 rr[16];
      #pragma unroll
      for (int j = 0; j < 16; ++j) {
        ss[j] = __shfl(sv,  j, 16);
        ww[j] = __shfl(wvv, j, 16);
      }
      #pragma unroll
      for (int j = 0; j < 16; ++j) rr[j] = *(const uint2*)(xb + (size_t)ss[j] * 256);
      #pragma unroll
      for (int j = 0; j < 16; ++j) {
        const __half2* p = (const __half2*)&rr[j];
        const float2 lo = __half22float2(p[0]), hi = __half22float2(p[1]);
        den += ww[j];
        a0 += ww[j] * lo.x; a1 += ww[j] * lo.y;
        a2 += ww[j] * hi.x; a3 += ww[j] * hi.y;
      }
    } else {
      for (int j = 0; j < cnt; ++j) {
        const int   s = __shfl(sv, j, 16);
        const float w = __shfl(wvv, j, 16);
        const uint2 r = *(const uint2*)(xb + (size_t)s * 256);
        const __half2* p = (const __half2*)&r;
        const float2 lo = __half22float2(p[0]), hi = __half22float2(p[1]);
        den += w;
        a0 += w * lo.x; a1 += w * lo.y; a2 += w * hi.x; a3 += w * hi.y;
      }
    }
  }

  __shared__ float ra[256];
  __shared__ float rd[64];
  if (wv == 1) {
    ra[lane * 4 + 0] = a0; ra[lane * 4 + 1] = a1;
    ra[lane * 4 + 2] = a2; ra[lane * 4 + 3] = a3;
    rd[lane] = den;
  }
  __syncthreads();
  if (wv == 0) {
    a0 += ra[lane * 4 + 0]; a1 += ra[lane * 4 + 1];
    a2 += ra[lane * 4 + 2]; a3 += ra[lane * 4 + 3];
    den += rd[lane];
    const float inv = 1.f / (den + 1e-16f);
    const float4 bv = *(const float4*)(bias + lane * 4);
    float o0 = a0 * inv + bv.x, o1 = a1 * inv + bv.y;
    float o2 = a2 * inv + bv.z, o3 = a3 * inv + bv.w;
    o0 = o0 > 0.f ? o0 : 0.01f * o0;
    o1 = o1 > 0.f ? o1 : 0.01f * o1;
    o2 = o2 > 0.f ? o2 : 0.01f * o2;
    o3 = o3 > 0.f ? o3 : 0.01f * o3;
    const __half2 p0 = __floats2half2_rn(o0, o1), p1 = __floats2half2_rn(o2, o3);
    uint2 st;
    st.x = *(const unsigned*)&p0;
    st.y = *(const unsigned*)&p1;
    *(uint2*)(h + (size_t)n * 256 + lane * 4) = st;
  }
}

// ---------------------------------------------------------------------------
// Edge scoring via MFMA over FLAT 16-edge chunks, SOFTWARE-PIPELINED:
// chunk n+1's se + row gathers are issued before chunk n's compute, so each
// wave holds ~2 chunks of loads in flight (one latency per chunk instead of
// two serial ones: se -> rows). dst-rows cache-hot (CSR order).
// ---------------------------------------------------------------------------
__global__ __launch_bounds__(256) void k_score_flat(
    const _Float16* __restrict__ h, const int4* __restrict__ se,
    const _Float16* __restrict__ wt3h, const float* __restrict__ fc1b,
    float* __restrict__ out, int total_waves) {
  const int lane = threadIdx.x & 63;
  const int q = lane >> 4, l16 = lane & 15;
  const int wgid = blockIdx.x * 4 + (threadIdx.x >> 6);

  v8hf bfrag[8];
  {
    const _Float16* brow = wt3h + l16 * 256 + q * 8;
    #pragma unroll
    for (int kci = 0; kci < 8; ++kci) bfrag[kci] = *(const v8hf*)(brow + kci * 32);
  }
  const float bn = (l16 < 3) ? fc1b[l16] : 0.f;

  int ch = wgid;
  if (ch >= CH) return;

  int4 p; v8hf av[8], dv[8];
  {
    const int idx = ch * 16 + l16;
    p = make_int4(0, -1, 0, 0);
    if (idx < EL) p = se[idx];
    const _Float16* srow = h + (size_t)p.x * 256 + q * 8;
    const _Float16* drow = h + (size_t)p.z * 256 + q * 8;
    #pragma unroll
    for (int k = 0; k < 8; ++k) av[k] = *(const v8hf*)(srow + k * 32);
    #pragma unroll
    for (int k = 0; k < 8; ++k) dv[k] = *(const v8hf*)(drow + k * 32);
  }

  while (true) {
    const int chn = ch + total_waves;
    const bool more = (chn < CH);
    int4 pn = make_int4(0, -1, 0, 0);
    v8hf avn[8], dvn[8];
    if (more) {
      const int idx = chn * 16 + l16;
      if (idx < EL) pn = se[idx];
      const _Float16* srow = h + (size_t)pn.x * 256 + q * 8;
      const _Float16* drow = h + (size_t)pn.z * 256 + q * 8;
      #pragma unroll
      for (int k = 0; k < 8; ++k) avn[k] = *(const v8hf*)(srow + k * 32);
      #pragma unroll
      for (int k = 0; k < 8; ++k) dvn[k] = *(const v8hf*)(drow + k * 32);
    }

    // compute current chunk
    v4f acc = {0.f, 0.f, 0.f, 0.f};
    #pragma unroll
    for (int kci = 0; kci < 8; ++kci) {
      const v8hf ar = av[kci] * dv[kci];     // v_pk_mul_f16 x4
      acc = __builtin_amdgcn_mfma_f32_16x16x32_f16(ar, bfrag[kci], acc, 0, 0, 0);
    }
    #pragma unroll
    for (int r = 0; r < 4; ++r) {
      const int m = q * 4 + r;
      const int em = __shfl(p.y, m, 16);     // eid lives in lane l16==m of group
      if (l16 < 3 && em >= 0)
        out[(size_t)em * 3 + l16] = acc[r] + bn;
    }

    if (!more) break;
    ch = chn; p = pn;
    #pragma unroll
    for (int k = 0; k < 8; ++k) { av[k] = avn[k]; dv[k] = dvn[k]; }
  }
}

// ---------------------------------------------------------------------------
static inline size_t align256(size_t b) { return (b + 255) & ~(size_t)255; }

extern "C" void kernel_launch(void* const* d_in, const int* in_sizes, int n_in,
                              void* d_out, int out_size, void* d_ws, size_t ws_size,
                              hipStream_t stream) {
  const float* x    = (const float*)d_in[0];
  const int*   ei   = (const int*)  d_in[1];   // [2,E] flat: [0:E]=src, [E:2E]=dst
  const float* W    = (const float*)d_in[2];
  const float* attS = (const float*)d_in[3];
  const float* attD = (const float*)d_in[4];
  const float* bias = (const float*)d_in[5];
  const float* fc1W = (const float*)d_in[6];
  const float* fc1b = (const float*)d_in[7];
  float*       out  = (float*)d_out;
  char*        ws   = (char*)d_ws;

  size_t off = 0;
  auto alloc = [&](size_t bytes) -> void* {
    void* p = ws + off;
    off += align256(bytes);
    return p;
  };
  _Float16* wt     = (_Float16*)alloc((size_t)F * F * sizeof(_Float16));  // 128 KB
  _Float16* wt3h   = (_Float16*)alloc((size_t)16 * F * sizeof(_Float16)); // 8 KB
  __half*   xp     = (__half*)  alloc((size_t)N * F * sizeof(__half));    // 25.6 MB
  __half*   hbuf   = (__half*)  alloc((size_t)N * F * sizeof(__half));    // 25.6 MB
  float*    a_src  = (float*)   alloc((size_t)N * 4 * sizeof(float));
  float*    a_dst  = (float*)   alloc((size_t)N * 4 * sizeof(float));
  int*      counts = (int*)     alloc((size_t)N * sizeof(int));
  int*      offs   = (int*)     alloc((size_t)(N + 1) * sizeof(int));
  int*      partial= (int*)     alloc(256 * sizeof(int));
  int*      cursor = (int*)     alloc((size_t)N * sizeof(int));
  int4*     se     = (int4*)    alloc((size_t)EL * sizeof(int4));         // 26.4 MB

  k_prep<<<256, 256, 0, stream>>>(W, fc1W, wt, wt3h, counts);
  k_xw_mfma<<<N / 16, 256, 0, stream>>>(x, wt, attS, attD, ei, counts,
                                        xp, a_src, a_dst);
  k_scan1<<<NBLK, 256, 0, stream>>>(counts, offs, partial);
  k_scan3b<<<NBLK, 256, 0, stream>>>(offs, partial, cursor);
  k_scatter<<<(EL + 255) / 256, 256, 0, stream>>>(ei, cursor, se);
  k_agg<<<N, 128, 0, stream>>>(xp, a_src, a_dst, se, offs, bias, hbuf);
  const int score_blocks = 4096;
  k_score_flat<<<score_blocks, 256, 0, stream>>>((const _Float16*)hbuf, se, wt3h,
                                                 fc1b, out, score_blocks * 4);
}